// Round 4
// baseline (135.868 us; speedup 1.0000x reference)
//
#include <hip/hip_runtime.h>
#include <hip/hip_bf16.h>
#include <stdint.h>

#define N    8192
#define D    256
#define NCLS 100

static constexpr float TEMP    = 0.5f;
static constexpr float SCALE_F = 1.69864360f;  // sqrt(log2e/TEMP)
static constexpr float LN2     = 0.69314718055994531f;

typedef float f32x4 __attribute__((ext_vector_type(4)));

__device__ __forceinline__ unsigned short f2bf(float f) {
  union { float f; unsigned int u; } x; x.f = f;
  unsigned int r = x.u + 0x7fffu + ((x.u >> 16) & 1u);
  return (unsigned short)(r >> 16);
}
__device__ __forceinline__ float bf2f(unsigned short b) {
  union { unsigned int u; float f; } x; x.u = ((unsigned int)b) << 16;
  return x.f;
}

// fp8 fragment-major layout:
//   addr(r, k) = (r>>4)*4096 + (k>>3)*128 + (r&15)*8 + (k&7)
// -> every fragment read is a lane-linear 512B segment: one coalesced
//    global_load_dwordx2 per wave, L2-resident (matrix is 2 MB).

// ---- Kernel A: row-normalize; bf16 row-major copy (class sums) + fp8 e4m3
// fragment-major copy (GEMM); also zeroes rowsum (folds the memset).
__global__ __launch_bounds__(256) void normalize_kernel(
    const float* __restrict__ emb, const long long* __restrict__ label,
    unsigned short* __restrict__ abf, unsigned char* __restrict__ a8,
    float* __restrict__ rowsum, int* __restrict__ cnt,
    int* __restrict__ list) {
  const int row  = blockIdx.x * 4 + (threadIdx.x >> 6);
  const int lane = threadIdx.x & 63;
  const float4 v = ((const float4*)(emb + (size_t)row * D))[lane];
  float ss = v.x * v.x + v.y * v.y + v.z * v.z + v.w * v.w;
#pragma unroll
  for (int off = 1; off < 64; off <<= 1) ss += __shfl_xor(ss, off);
  const float s = rsqrtf(ss) * SCALE_F;
  const float x = v.x * s, y = v.y * s, z = v.z * s, wv = v.w * s;

  ushort4 o;
  o.x = f2bf(x); o.y = f2bf(y); o.z = f2bf(z); o.w = f2bf(wv);
  ((ushort4*)(abf + (size_t)row * D))[lane] = o;

  int p = __builtin_amdgcn_cvt_pk_fp8_f32(x, y, 0, false);
  p = __builtin_amdgcn_cvt_pk_fp8_f32(z, wv, p, true);
  // k = lane*4 .. +3 -> octet = lane>>1, 4B half = lane&1
  *(int*)(a8 + (size_t)(row >> 4) * 4096 + (lane >> 1) * 128 +
          (row & 15) * 8 + (lane & 1) * 4) = p;

  if (lane == 0) {
    rowsum[row] = 0.f;
    const int c = (int)label[row];
    const int slot = atomicAdd(cnt + c, 1);
    list[c * 256 + slot] = row;
  }
}

// ---- Kernel B: symmetric (strict upper triangle). exp(sim) is bit-exactly
// symmetric (same fp8 products, same K accumulation order), so each upper
// element feeds rowsum[i] (row reduce) AND rowsum[j] (col reduce + atomic).
//
// R3 restructure (parallelism-deficit fix): R1/R2 had only 544 blocks =
// 2.1 waves/SIMD — nothing to hide L2 latency with (all pipes idle in the
// counters). Now: ONE block per live 128x128 sub-tile (2080 blocks = 8.1
// waves/SIMD demand), NO LDS, NO barriers. A and B fragments both read
// directly global->reg (L2-resident; 512B coalesced segments). Occupancy
// is VGPR-bound only: launch_bounds(256,4) caps at 128 VGPR (est ~105)
// -> 4 waves/SIMD resident, asynchronous block drain/refill.
__global__ __launch_bounds__(256, 4) void simexp_rowsum_kernel(
    const unsigned char* __restrict__ A, float* __restrict__ rowsum) {
  const int tid  = threadIdx.x;
  const int w    = tid >> 6;
  const int lane = tid & 63;
  const int quad = lane >> 4;
  const int l15  = lane & 15;

  // Triangular decode over 64x64 tile grid, upper incl. diagonal:
  // b -> (x, y) with y <= x; row tile = y, col tile = x.
  const int b = blockIdx.x;
  int x = (int)((-1.0f + sqrtf(1.0f + 8.0f * (float)b)) * 0.5f);
  while ((x + 1) * (x + 2) / 2 <= b) ++x;
  while (x * (x + 1) / 2 > b) --x;
  const int y = b - x * (x + 1) / 2;

  const int row0 = y << 7;
  const int col0 = x << 7;
  const bool diag = (x == y);
  const int wm  = (w & 1) * 64;   // wave's row half
  const int jn0 = (w >> 1) * 64;  // wave's col half
  // Diagonal sub-tile, wave region entirely strictly-lower: nothing to do.
  if (diag && wm > jn0) return;
  const bool needmask = diag && (wm == jn0);

  const unsigned char* Ap = A + (size_t)((row0 >> 4) + (w & 1) * 4) * 4096;
  const unsigned char* Bp = A + (size_t)((col0 >> 4) + (w >> 1) * 4) * 4096;

  f32x4 acc[4][4];
#pragma unroll
  for (int mt = 0; mt < 4; ++mt)
#pragma unroll
    for (int nt = 0; nt < 4; ++nt) acc[mt][nt] = (f32x4){0.f, 0.f, 0.f, 0.f};

#pragma unroll
  for (int kq = 0; kq < 4; ++kq) {
#pragma unroll
    for (int kkl = 0; kkl < 2; ++kkl) {
      const int fo = kq * 1024 + (kkl * 4 + quad) * 128 + l15 * 8;
      long af[4], bf[4];
#pragma unroll
      for (int mt = 0; mt < 4; ++mt)
        af[mt] = *(const long*)(Ap + mt * 4096 + fo);
#pragma unroll
      for (int nt = 0; nt < 4; ++nt)
        bf[nt] = *(const long*)(Bp + nt * 4096 + fo);
#pragma unroll
      for (int mt = 0; mt < 4; ++mt)
#pragma unroll
        for (int nt = 0; nt < 4; ++nt)
          acc[mt][nt] = __builtin_amdgcn_mfma_f32_16x16x32_fp8_fp8(
              af[mt], bf[nt], acc[mt][nt], 0, 0, 0);
    }
  }

  // Epilogue: exp2, diagonal mask, row partials + column partials.
  float rowpart[4][4];
  float colpart[4] = {0.f, 0.f, 0.f, 0.f};
#pragma unroll
  for (int mt = 0; mt < 4; ++mt)
#pragma unroll
    for (int e = 0; e < 4; ++e) rowpart[mt][e] = 0.f;
#pragma unroll
  for (int mt = 0; mt < 4; ++mt)
#pragma unroll
    for (int nt = 0; nt < 4; ++nt)
#pragma unroll
      for (int e = 0; e < 4; ++e) {
        float v = __builtin_amdgcn_exp2f(acc[mt][nt][e]);
        if (needmask) {
          const int iw = mt * 16 + quad * 4 + e;  // row within wave region
          const int jw = nt * 16 + l15;           // col within wave region
          v = (iw < jw) ? v : 0.f;
        }
        rowpart[mt][e] += v;
        colpart[nt] += v;
      }

  // Column reduce over rows (lane bits 4,5), one atomic per column per wave.
#pragma unroll
  for (int nt = 0; nt < 4; ++nt) {
    float v = colpart[nt];
    v += __shfl_xor(v, 16);
    v += __shfl_xor(v, 32);
    if (quad == 0)
      atomicAdd(&rowsum[col0 + jn0 + nt * 16 + l15], v);
  }
  // Row reduce: C layout col = l15, row-in-16 = quad*4 + e. Reduce over 16
  // cols, one atomic per row per wave.
#pragma unroll
  for (int mt = 0; mt < 4; ++mt)
#pragma unroll
    for (int e = 0; e < 4; ++e) {
      float v = rowpart[mt][e];
      v += __shfl_xor(v, 1);
      v += __shfl_xor(v, 2);
      v += __shfl_xor(v, 4);
      v += __shfl_xor(v, 8);
      if (l15 == 0)
        atomicAdd(&rowsum[row0 + wm + mt * 16 + quad * 4 + e], v);
    }
}

__global__ __launch_bounds__(256) void finalize_kernel(
    const unsigned short* __restrict__ abf, const float* __restrict__ rowsum,
    const long long* __restrict__ label, const int* __restrict__ cnt,
    const int* __restrict__ list, float* __restrict__ out) {
  __shared__ float red[4];
  __shared__ int rows_l[256];
  const int tid  = threadIdx.x;
  const int w    = tid >> 6;
  const int lane = tid & 63;

  if (blockIdx.x < NCLS) {
    const int c = blockIdx.x;
    const int m = cnt[c];
    if (m <= 1) return;
    if (tid < m) rows_l[tid] = list[c * 256 + tid];
    __syncthreads();
    float acc = 0.f;
    for (int s = 0; s < m; ++s)
      acc += bf2f(abf[(size_t)rows_l[s] * D + tid]);
    float v = acc * acc;
#pragma unroll
    for (int off = 1; off < 64; off <<= 1) v += __shfl_xor(v, off);
    if (lane == 0) red[w] = v;
    __syncthreads();
    if (tid == 0) {
      const float ssq = red[0] + red[1] + red[2] + red[3];
      const float term = (ssq * LN2 - 2.0f * (float)m) / (float)(m - 1);
      atomicAdd(out, -term);
    }
  } else {
    // rowsum already excludes the diagonal (strict upper triangle only).
    const int i = (blockIdx.x - NCLS) * 256 + tid;
    const int c = (int)label[i];
    float v = 0.f;
    if (cnt[c] > 1)
      v = __builtin_amdgcn_logf(rowsum[i]) * LN2;
#pragma unroll
    for (int off = 1; off < 64; off <<= 1) v += __shfl_xor(v, off);
    if (lane == 0) red[w] = v;
    __syncthreads();
    if (tid == 0)
      atomicAdd(out, red[0] + red[1] + red[2] + red[3]);
  }
}

extern "C" void kernel_launch(void* const* d_in, const int* in_sizes, int n_in,
                              void* d_out, int out_size, void* d_ws,
                              size_t ws_size, hipStream_t stream) {
  const float* emb = (const float*)d_in[0];
  const long long* label = (const long long*)d_in[1];
  float* out = (float*)d_out;

  char* ws = (char*)d_ws;
  unsigned short* abf = (unsigned short*)ws;            // 4 MB bf16 row-major
  unsigned char* a8 = (unsigned char*)(ws + (size_t)N * D * 2);  // 2 MB fp8
  float* rowsum = (float*)(ws + (size_t)N * D * 3);     // N floats
  int* cnt = (int*)(rowsum + N);                        // 128 ints
  int* list = cnt + 128;                                // NCLS*256 ints

  hipMemsetAsync(cnt, 0, 128 * 4, stream);
  hipMemsetAsync(out, 0, sizeof(float), stream);

  normalize_kernel<<<N / 4, 256, 0, stream>>>(emb, label, abf, a8, rowsum,
                                              cnt, list);

  // One block per live upper-triangle 128x128 sub-tile: 64*65/2 = 2080.
  simexp_rowsum_kernel<<<2080, 256, 0, stream>>>(a8, rowsum);

  finalize_kernel<<<NCLS + N / 256, 256, 0, stream>>>(abf, rowsum, label, cnt,
                                                      list, out);
}

// Round 5
// 130.642 us; speedup vs baseline: 1.0400x; 1.0400x over previous
//
#include <hip/hip_runtime.h>
#include <hip/hip_bf16.h>
#include <stdint.h>

#define N    8192
#define D    256
#define NCLS 100

static constexpr float TEMP    = 0.5f;
static constexpr float SCALE_F = 1.69864360f;  // sqrt(log2e/TEMP)
static constexpr float LN2     = 0.69314718055994531f;

// Per-band partial slots: 64 bands x 130 slots x 128 rows (see simexp).
#define NSLOT 130

typedef float f32x4 __attribute__((ext_vector_type(4)));

__device__ __forceinline__ unsigned short f2bf(float f) {
  union { float f; unsigned int u; } x; x.f = f;
  unsigned int r = x.u + 0x7fffu + ((x.u >> 16) & 1u);
  return (unsigned short)(r >> 16);
}
__device__ __forceinline__ float bf2f(unsigned short b) {
  union { unsigned int u; float f; } x; x.u = ((unsigned int)b) << 16;
  return x.f;
}

// fp8 fragment-major layout:
//   addr(r, k) = (r>>4)*4096 + (k>>3)*128 + (r&15)*8 + (k&7)
// -> every fragment read is a lane-linear 512B segment: one coalesced
//    global_load_dwordx2 per wave, L2-resident (matrix is 2 MB).

// ---- Kernel A: row-normalize; bf16 row-major copy (class sums) + fp8 e4m3
// fragment-major copy (GEMM).
__global__ __launch_bounds__(256) void normalize_kernel(
    const float* __restrict__ emb, const long long* __restrict__ label,
    unsigned short* __restrict__ abf, unsigned char* __restrict__ a8,
    int* __restrict__ cnt, int* __restrict__ list) {
  const int row  = blockIdx.x * 4 + (threadIdx.x >> 6);
  const int lane = threadIdx.x & 63;
  const float4 v = ((const float4*)(emb + (size_t)row * D))[lane];
  float ss = v.x * v.x + v.y * v.y + v.z * v.z + v.w * v.w;
#pragma unroll
  for (int off = 1; off < 64; off <<= 1) ss += __shfl_xor(ss, off);
  const float s = rsqrtf(ss) * SCALE_F;
  const float x = v.x * s, y = v.y * s, z = v.z * s, wv = v.w * s;

  ushort4 o;
  o.x = f2bf(x); o.y = f2bf(y); o.z = f2bf(z); o.w = f2bf(wv);
  ((ushort4*)(abf + (size_t)row * D))[lane] = o;

  int p = __builtin_amdgcn_cvt_pk_fp8_f32(x, y, 0, false);
  p = __builtin_amdgcn_cvt_pk_fp8_f32(z, wv, p, true);
  // k = lane*4 .. +3 -> octet = lane>>1, 4B half = lane&1
  *(int*)(a8 + (size_t)(row >> 4) * 4096 + (lane >> 1) * 128 +
          (row & 15) * 8 + (lane & 1) * 4) = p;

  if (lane == 0) {
    const int c = (int)label[row];
    const int slot = atomicAdd(cnt + c, 1);
    list[c * 256 + slot] = row;
  }
}

// ---- Kernel B: symmetric (strict upper triangle), one block per live
// 128x128 sub-tile (2080 blocks), no LDS, no barriers, A and B fragments
// direct global->reg (L2-resident; coalesced 512B segments).
//
// R5 change (atomic-serialization fix): R1/R2/R4 all sat at ~44 us with
// every pipe idle regardless of structure; shared element was ~1M
// atomicAdds into rowsum (est. 27-55 us at 1-2 RMW/cyc/XCD). Replaced by
// PLAIN STORES of per-block partials into a bijective (band, slot, idx)
// buffer — no RMW, no serialization, waves retire immediately.
//
// Slot map for band t (rows t*128..t*128+127), NSLOT=130 slots:
//   row-side, block (x,y=t), wave col-half jh=jn0>>6 -> slot 2x+jh
//     (x = t..63; covers slots 2t..127)
//   col-side, block (x=t,y<t), wave row-half rh=wm>>6 -> slot 2y+rh
//     (y = 0..t-1; covers slots 0..2t-1)
//   col-side of DIAGONAL block (t,t) -> slots 128+rh
// Every (band, slot, idx) has exactly one writer (diag's dead wave w1
// writes zeros to its two regions), so no zero-init pass is needed.
__global__ __launch_bounds__(256, 4) void simexp_rowsum_kernel(
    const unsigned char* __restrict__ A, float* __restrict__ part) {
  const int tid  = threadIdx.x;
  const int w    = tid >> 6;
  const int lane = tid & 63;
  const int quad = lane >> 4;
  const int l15  = lane & 15;

  // Triangular decode over 64x64 tile grid, upper incl. diagonal:
  // b -> (x, y) with y <= x; row tile = y, col tile = x.
  const int b = blockIdx.x;
  int x = (int)((-1.0f + sqrtf(1.0f + 8.0f * (float)b)) * 0.5f);
  while ((x + 1) * (x + 2) / 2 <= b) ++x;
  while (x * (x + 1) / 2 > b) --x;
  const int y = b - x * (x + 1) / 2;

  const int row0 = y << 7;
  const int col0 = x << 7;
  const bool diag = (x == y);
  const int wm  = (w & 1) * 64;   // wave's row half
  const int jn0 = (w >> 1) * 64;  // wave's col half

  // Diagonal sub-tile, wave region entirely strictly-lower: contributes
  // nothing, but must still fill its partial slots (coverage invariant).
  if (diag && wm > jn0) {  // only w=1: rows 64..127, cols 0..63
    part[((size_t)y * NSLOT + 2 * x + 0) * 128 + 64 + lane] = 0.f;   // rowside
    part[((size_t)x * NSLOT + 128 + 1) * 128 + lane] = 0.f;          // colside
    return;
  }
  const bool needmask = diag && (wm == jn0);

  const unsigned char* Ap = A + (size_t)((row0 >> 4) + (w & 1) * 4) * 4096;
  const unsigned char* Bp = A + (size_t)((col0 >> 4) + (w >> 1) * 4) * 4096;

  f32x4 acc[4][4];
#pragma unroll
  for (int mt = 0; mt < 4; ++mt)
#pragma unroll
    for (int nt = 0; nt < 4; ++nt) acc[mt][nt] = (f32x4){0.f, 0.f, 0.f, 0.f};

#pragma unroll
  for (int kq = 0; kq < 4; ++kq) {
#pragma unroll
    for (int kkl = 0; kkl < 2; ++kkl) {
      const int fo = kq * 1024 + (kkl * 4 + quad) * 128 + l15 * 8;
      long af[4], bf[4];
#pragma unroll
      for (int mt = 0; mt < 4; ++mt)
        af[mt] = *(const long*)(Ap + mt * 4096 + fo);
#pragma unroll
      for (int nt = 0; nt < 4; ++nt)
        bf[nt] = *(const long*)(Bp + nt * 4096 + fo);
#pragma unroll
      for (int mt = 0; mt < 4; ++mt)
#pragma unroll
        for (int nt = 0; nt < 4; ++nt)
          acc[mt][nt] = __builtin_amdgcn_mfma_f32_16x16x32_fp8_fp8(
              af[mt], bf[nt], acc[mt][nt], 0, 0, 0);
    }
  }

  // Epilogue: exp2, diagonal mask, row partials + column partials.
  float rowpart[4][4];
  float colpart[4] = {0.f, 0.f, 0.f, 0.f};
#pragma unroll
  for (int mt = 0; mt < 4; ++mt)
#pragma unroll
    for (int e = 0; e < 4; ++e) rowpart[mt][e] = 0.f;
#pragma unroll
  for (int mt = 0; mt < 4; ++mt)
#pragma unroll
    for (int nt = 0; nt < 4; ++nt)
#pragma unroll
      for (int e = 0; e < 4; ++e) {
        float v = __builtin_amdgcn_exp2f(acc[mt][nt][e]);
        if (needmask) {
          const int iw = mt * 16 + quad * 4 + e;  // row within wave region
          const int jw = nt * 16 + l15;           // col within wave region
          v = (iw < jw) ? v : 0.f;
        }
        rowpart[mt][e] += v;
        colpart[nt] += v;
      }

  // Partial destinations (plain stores, each address written exactly once).
  const int rslot = 2 * x + (jn0 >> 6);
  const int cslot = diag ? (128 + (wm >> 6)) : (2 * y + (wm >> 6));
  float* rowdst = part + ((size_t)y * NSLOT + rslot) * 128 + wm;
  float* coldst = part + ((size_t)x * NSLOT + cslot) * 128 + jn0;

  // Column reduce over rows (lane bits 4,5): lanes quad==0 hold 16 cols.
#pragma unroll
  for (int nt = 0; nt < 4; ++nt) {
    float v = colpart[nt];
    v += __shfl_xor(v, 16);
    v += __shfl_xor(v, 32);
    if (quad == 0) coldst[nt * 16 + l15] = v;
  }
  // Row reduce over 16 cols (lane bits 0..3): lanes l15==0 (one per quad)
  // hold rows quad*4+e+mt*16.
#pragma unroll
  for (int mt = 0; mt < 4; ++mt)
#pragma unroll
    for (int e = 0; e < 4; ++e) {
      float v = rowpart[mt][e];
      v += __shfl_xor(v, 1);
      v += __shfl_xor(v, 2);
      v += __shfl_xor(v, 4);
      v += __shfl_xor(v, 8);
      if (l15 == 0) rowdst[mt * 16 + quad * 4 + e] = v;
    }
}

__global__ __launch_bounds__(256) void finalize_kernel(
    const unsigned short* __restrict__ abf, const float* __restrict__ part,
    const long long* __restrict__ label, const int* __restrict__ cnt,
    const int* __restrict__ list, float* __restrict__ out) {
  __shared__ float red[4];
  __shared__ int rows_l[256];
  const int tid  = threadIdx.x;
  const int w    = tid >> 6;
  const int lane = tid & 63;

  if (blockIdx.x < NCLS) {
    const int c = blockIdx.x;
    const int m = cnt[c];
    if (m <= 1) return;
    if (tid < m) rows_l[tid] = list[c * 256 + tid];
    __syncthreads();
    float acc = 0.f;
    for (int s = 0; s < m; ++s)
      acc += bf2f(abf[(size_t)rows_l[s] * D + tid]);
    float v = acc * acc;
#pragma unroll
    for (int off = 1; off < 64; off <<= 1) v += __shfl_xor(v, off);
    if (lane == 0) red[w] = v;
    __syncthreads();
    if (tid == 0) {
      const float ssq = red[0] + red[1] + red[2] + red[3];
      const float term = (ssq * LN2 - 2.0f * (float)m) / (float)(m - 1);
      atomicAdd(out, -term);
    }
  } else {
    // rowsum_i = sum of the 130 per-block partials for this row's band.
    // Coalesced: for fixed s, consecutive tid -> consecutive addresses.
    const int i = (blockIdx.x - NCLS) * 256 + tid;
    const int band = i >> 7, r = i & 127;
    const float* ps = part + (size_t)band * NSLOT * 128 + r;
    float rs = 0.f;
#pragma unroll 13
    for (int s = 0; s < NSLOT; ++s) rs += ps[(size_t)s * 128];
    const int c = (int)label[i];
    float v = 0.f;
    if (cnt[c] > 1)
      v = __builtin_amdgcn_logf(rs) * LN2;
#pragma unroll
    for (int off = 1; off < 64; off <<= 1) v += __shfl_xor(v, off);
    if (lane == 0) red[w] = v;
    __syncthreads();
    if (tid == 0)
      atomicAdd(out, red[0] + red[1] + red[2] + red[3]);
  }
}

extern "C" void kernel_launch(void* const* d_in, const int* in_sizes, int n_in,
                              void* d_out, int out_size, void* d_ws,
                              size_t ws_size, hipStream_t stream) {
  const float* emb = (const float*)d_in[0];
  const long long* label = (const long long*)d_in[1];
  float* out = (float*)d_out;

  char* ws = (char*)d_ws;
  unsigned short* abf = (unsigned short*)ws;            // 4 MB bf16 row-major
  unsigned char* a8 = (unsigned char*)(ws + (size_t)N * D * 2);  // 2 MB fp8
  float* part = (float*)(ws + (size_t)N * D * 3);       // 64*130*128 f32
  int* cnt = (int*)(ws + (size_t)N * D * 3 + (size_t)64 * NSLOT * 128 * 4);
  int* list = cnt + 128;                                // NCLS*256 ints

  hipMemsetAsync(cnt, 0, 128 * 4, stream);
  hipMemsetAsync(out, 0, sizeof(float), stream);

  normalize_kernel<<<N / 4, 256, 0, stream>>>(emb, label, abf, a8, cnt, list);

  // One block per live upper-triangle 128x128 sub-tile: 64*65/2 = 2080.
  simexp_rowsum_kernel<<<2080, 256, 0, stream>>>(a8, part);

  finalize_kernel<<<NCLS + N / 256, 256, 0, stream>>>(abf, part, label, cnt,
                                                      list, out);
}

// Round 6
// 127.810 us; speedup vs baseline: 1.0630x; 1.0222x over previous
//
#include <hip/hip_runtime.h>
#include <hip/hip_bf16.h>
#include <stdint.h>

#define N    8192
#define D    256
#define NCLS 100

static constexpr float TEMP    = 0.5f;
static constexpr float SCALE_F = 1.69864360f;  // sqrt(log2e/TEMP)
static constexpr float LN2     = 0.69314718055994531f;

// Per-band partial slots: 64 bands x 130 slots x 128 rows (see simexp).
#define NSLOT 130

typedef float f32x4 __attribute__((ext_vector_type(4)));

__device__ __forceinline__ unsigned short f2bf(float f) {
  union { float f; unsigned int u; } x; x.f = f;
  unsigned int r = x.u + 0x7fffu + ((x.u >> 16) & 1u);
  return (unsigned short)(r >> 16);
}
__device__ __forceinline__ float bf2f(unsigned short b) {
  union { unsigned int u; float f; } x; x.u = ((unsigned int)b) << 16;
  return x.f;
}
__device__ __forceinline__ void gld16(const void* g, void* l) {
  __builtin_amdgcn_global_load_lds(
      (const __attribute__((address_space(1))) unsigned int*)g,
      (__attribute__((address_space(3))) unsigned int*)l, 16, 0, 0);
}

// fp8 fragment-major layout:
//   addr(r, k) = (r>>4)*4096 + (k>>3)*128 + (r&15)*8 + (k&7)
// -> staging is a flat contiguous copy (gld16, wave-uniform base + lane*16);
// -> LDS fragment reads are lane-linear 512B segments (0 bank conflicts).

// ---- Kernel A: row-normalize; bf16 row-major copy (class sums) + fp8 e4m3
// fragment-major copy (GEMM).
__global__ __launch_bounds__(256) void normalize_kernel(
    const float* __restrict__ emb, const long long* __restrict__ label,
    unsigned short* __restrict__ abf, unsigned char* __restrict__ a8,
    int* __restrict__ cnt, int* __restrict__ list) {
  const int row  = blockIdx.x * 4 + (threadIdx.x >> 6);
  const int lane = threadIdx.x & 63;
  const float4 v = ((const float4*)(emb + (size_t)row * D))[lane];
  float ss = v.x * v.x + v.y * v.y + v.z * v.z + v.w * v.w;
#pragma unroll
  for (int off = 1; off < 64; off <<= 1) ss += __shfl_xor(ss, off);
  const float s = rsqrtf(ss) * SCALE_F;
  const float x = v.x * s, y = v.y * s, z = v.z * s, wv = v.w * s;

  ushort4 o;
  o.x = f2bf(x); o.y = f2bf(y); o.z = f2bf(z); o.w = f2bf(wv);
  ((ushort4*)(abf + (size_t)row * D))[lane] = o;

  int p = __builtin_amdgcn_cvt_pk_fp8_f32(x, y, 0, false);
  p = __builtin_amdgcn_cvt_pk_fp8_f32(z, wv, p, true);
  // k = lane*4 .. +3 -> octet = lane>>1, 4B half = lane&1
  *(int*)(a8 + (size_t)(row >> 4) * 4096 + (lane >> 1) * 128 +
          (row & 15) * 8 + (lane & 1) * 4) = p;

  if (lane == 0) {
    const int c = (int)label[row];
    const int slot = atomicAdd(cnt + c, 1);
    list[c * 256 + slot] = row;
  }
}

// ---- Kernel B: symmetric (strict upper triangle), one block per live
// 128x128 sub-tile (2080 blocks).
//
// R6 change (MLP-starvation fix): R4/R5's direct global->reg loads gave
// each wave only ~1-2 loads in flight (8B result = 2 VGPR + 64b addr pair,
// VGPR-squeezed codegen) -> ~800 cyc exposed latency per load group, all
// pipes idle (MfmaUtil 13%). Now both 32 KB tiles are staged via
// global_load_lds: 16 async 16B ops per thread (zero VGPR cost, MLP=16),
// ONE vmcnt(0)+barrier drain per block (vs R1's eight), then all compute
// runs from LDS stall-free. 64 KB LDS -> 2 blocks/CU; while one block
// slot drains its stage the other computes (implicit wave overlap).
//
// Partial-sum slot map (bijective, plain stores, no atomics) — band t:
//   row-side, block (x,t), wave col-half jh -> slot 2x+jh   (slots 2t..127)
//   col-side, block (t,y<t), wave row-half rh -> slot 2y+rh (slots 0..2t-1)
//   col-side of diagonal block (t,t) -> slots 128+rh
// Every (band, slot, idx) written exactly once (diag dead wave writes 0s).
__global__ __launch_bounds__(256, 2) void simexp_rowsum_kernel(
    const unsigned char* __restrict__ A, float* __restrict__ part) {
  __shared__ __align__(16) unsigned char sa[128 * 256];  // 32 KB A tile
  __shared__ __align__(16) unsigned char sb[128 * 256];  // 32 KB B tile
  const int tid  = threadIdx.x;
  const int w    = tid >> 6;
  const int lane = tid & 63;
  const int quad = lane >> 4;
  const int l15  = lane & 15;

  // Triangular decode over 64x64 tile grid, upper incl. diagonal:
  // b -> (x, y) with y <= x; row tile = y, col tile = x.
  const int b = blockIdx.x;
  int x = (int)((-1.0f + sqrtf(1.0f + 8.0f * (float)b)) * 0.5f);
  while ((x + 1) * (x + 2) / 2 <= b) ++x;
  while (x * (x + 1) / 2 > b) --x;
  const int y = b - x * (x + 1) / 2;

  const int row0 = y << 7;
  const int col0 = x << 7;
  const bool diag = (x == y);
  const int wm  = (w & 1) * 64;   // wave's row half
  const int jn0 = (w >> 1) * 64;  // wave's col half

  // Stage A and B tiles: 32 segs of 1024 B each; wave w stages segs
  // w*8..w*8+7 of both. All 16 async ops issue back-to-back; single drain.
#pragma unroll
  for (int p = 0; p < 8; ++p) {
    const int seg = w * 8 + p;  // wave-uniform
    gld16(A + (size_t)((row0 >> 4) + (seg >> 2)) * 4096 + (seg & 3) * 1024 +
              lane * 16,
          sa + seg * 1024);
    gld16(A + (size_t)((col0 >> 4) + (seg >> 2)) * 4096 + (seg & 3) * 1024 +
              lane * 16,
          sb + seg * 1024);
  }
  __syncthreads();  // the only barrier (implicit vmcnt(0) drain)

  // Diagonal sub-tile, wave region entirely strictly-lower (only w=1):
  // contributes nothing, but must fill its partial slots (coverage
  // invariant). Exit AFTER the barrier (participation uniformity).
  if (diag && wm > jn0) {
    part[((size_t)y * NSLOT + 2 * x) * 128 + 64 + lane] = 0.f;  // row-side
    part[((size_t)x * NSLOT + 129) * 128 + lane] = 0.f;         // col-side
    return;
  }
  const bool needmask = diag && (wm == jn0);
  const int pam = (w & 1) * 4;   // wave's A panel base (local 16-row panels)
  const int pbn = (w >> 1) * 4;  // wave's B panel base

  f32x4 acc[4][4];
#pragma unroll
  for (int mt = 0; mt < 4; ++mt)
#pragma unroll
    for (int nt = 0; nt < 4; ++nt) acc[mt][nt] = (f32x4){0.f, 0.f, 0.f, 0.f};

#pragma unroll
  for (int kq = 0; kq < 4; ++kq) {
#pragma unroll
    for (int kkl = 0; kkl < 2; ++kkl) {
      const int fo = kq * 1024 + (kkl * 4 + quad) * 128 + l15 * 8;
      long af[4], bf[4];
#pragma unroll
      for (int mt = 0; mt < 4; ++mt)
        af[mt] = *(const long*)(sa + (pam + mt) * 4096 + fo);
#pragma unroll
      for (int nt = 0; nt < 4; ++nt)
        bf[nt] = *(const long*)(sb + (pbn + nt) * 4096 + fo);
#pragma unroll
      for (int mt = 0; mt < 4; ++mt)
#pragma unroll
        for (int nt = 0; nt < 4; ++nt)
          acc[mt][nt] = __builtin_amdgcn_mfma_f32_16x16x32_fp8_fp8(
              af[mt], bf[nt], acc[mt][nt], 0, 0, 0);
    }
  }

  // Epilogue: exp2, diagonal mask, row partials + column partials.
  float rowpart[4][4];
  float colpart[4] = {0.f, 0.f, 0.f, 0.f};
#pragma unroll
  for (int mt = 0; mt < 4; ++mt)
#pragma unroll
    for (int e = 0; e < 4; ++e) rowpart[mt][e] = 0.f;
#pragma unroll
  for (int mt = 0; mt < 4; ++mt)
#pragma unroll
    for (int nt = 0; nt < 4; ++nt)
#pragma unroll
      for (int e = 0; e < 4; ++e) {
        float v = __builtin_amdgcn_exp2f(acc[mt][nt][e]);
        if (needmask) {
          const int iw = mt * 16 + quad * 4 + e;  // row within wave region
          const int jw = nt * 16 + l15;           // col within wave region
          v = (iw < jw) ? v : 0.f;
        }
        rowpart[mt][e] += v;
        colpart[nt] += v;
      }

  // Partial destinations (plain stores, each address written exactly once).
  const int rslot = 2 * x + (jn0 >> 6);
  const int cslot = diag ? (128 + (wm >> 6)) : (2 * y + (wm >> 6));
  float* rowdst = part + ((size_t)y * NSLOT + rslot) * 128 + wm;
  float* coldst = part + ((size_t)x * NSLOT + cslot) * 128 + jn0;

  // Column reduce over rows (lane bits 4,5): lanes quad==0 hold 16 cols.
#pragma unroll
  for (int nt = 0; nt < 4; ++nt) {
    float v = colpart[nt];
    v += __shfl_xor(v, 16);
    v += __shfl_xor(v, 32);
    if (quad == 0) coldst[nt * 16 + l15] = v;
  }
  // Row reduce over 16 cols (lane bits 0..3): lanes l15==0 (one per quad)
  // hold rows quad*4+e+mt*16.
#pragma unroll
  for (int mt = 0; mt < 4; ++mt)
#pragma unroll
    for (int e = 0; e < 4; ++e) {
      float v = rowpart[mt][e];
      v += __shfl_xor(v, 1);
      v += __shfl_xor(v, 2);
      v += __shfl_xor(v, 4);
      v += __shfl_xor(v, 8);
      if (l15 == 0) rowdst[mt * 16 + quad * 4 + e] = v;
    }
}

__global__ __launch_bounds__(256) void finalize_kernel(
    const unsigned short* __restrict__ abf, const float* __restrict__ part,
    const long long* __restrict__ label, const int* __restrict__ cnt,
    const int* __restrict__ list, float* __restrict__ out) {
  __shared__ float red[4];
  __shared__ int rows_l[256];
  const int tid  = threadIdx.x;
  const int w    = tid >> 6;
  const int lane = tid & 63;

  if (blockIdx.x < NCLS) {
    const int c = blockIdx.x;
    const int m = cnt[c];
    if (m <= 1) return;
    if (tid < m) rows_l[tid] = list[c * 256 + tid];
    __syncthreads();
    float acc = 0.f;
    for (int s = 0; s < m; ++s)
      acc += bf2f(abf[(size_t)rows_l[s] * D + tid]);
    float v = acc * acc;
#pragma unroll
    for (int off = 1; off < 64; off <<= 1) v += __shfl_xor(v, off);
    if (lane == 0) red[w] = v;
    __syncthreads();
    if (tid == 0) {
      const float ssq = red[0] + red[1] + red[2] + red[3];
      const float term = (ssq * LN2 - 2.0f * (float)m) / (float)(m - 1);
      atomicAdd(out, -term);
    }
  } else {
    // rowsum_i = sum of the 130 per-block partials for this row's band.
    // Coalesced: for fixed s, consecutive tid -> consecutive addresses.
    const int i = (blockIdx.x - NCLS) * 256 + tid;
    const int band = i >> 7, r = i & 127;
    const float* ps = part + (size_t)band * NSLOT * 128 + r;
    float rs = 0.f;
#pragma unroll 13
    for (int s = 0; s < NSLOT; ++s) rs += ps[(size_t)s * 128];
    const int c = (int)label[i];
    float v = 0.f;
    if (cnt[c] > 1)
      v = __builtin_amdgcn_logf(rs) * LN2;
#pragma unroll
    for (int off = 1; off < 64; off <<= 1) v += __shfl_xor(v, off);
    if (lane == 0) red[w] = v;
    __syncthreads();
    if (tid == 0)
      atomicAdd(out, red[0] + red[1] + red[2] + red[3]);
  }
}

extern "C" void kernel_launch(void* const* d_in, const int* in_sizes, int n_in,
                              void* d_out, int out_size, void* d_ws,
                              size_t ws_size, hipStream_t stream) {
  const float* emb = (const float*)d_in[0];
  const long long* label = (const long long*)d_in[1];
  float* out = (float*)d_out;

  char* ws = (char*)d_ws;
  unsigned short* abf = (unsigned short*)ws;            // 4 MB bf16 row-major
  unsigned char* a8 = (unsigned char*)(ws + (size_t)N * D * 2);  // 2 MB fp8
  float* part = (float*)(ws + (size_t)N * D * 3);       // 64*130*128 f32
  int* cnt = (int*)(ws + (size_t)N * D * 3 + (size_t)64 * NSLOT * 128 * 4);
  int* list = cnt + 128;                                // NCLS*256 ints

  hipMemsetAsync(cnt, 0, 128 * 4, stream);
  hipMemsetAsync(out, 0, sizeof(float), stream);

  normalize_kernel<<<N / 4, 256, 0, stream>>>(emb, label, abf, a8, cnt, list);

  // One block per live upper-triangle 128x128 sub-tile: 64*65/2 = 2080.
  simexp_rowsum_kernel<<<2080, 256, 0, stream>>>(a8, part);

  finalize_kernel<<<NCLS + N / 256, 256, 0, stream>>>(abf, part, label, cnt,
                                                      list, out);
}